// Round 1
// baseline (360.847 us; speedup 1.0000x reference)
//
#include <hip/hip_runtime.h>
#include <math.h>

// Multi-scale region distillation loss.
// Scales: (H,W) = (128,128),(64,64),(32,32),(16,16); B=8, C=256; labels 8x1x512x512.
// Block = 512 threads = 8 waves. Each block: 64 pixel-groups (4 px each, float4),
// wave w handles channels [32w, 32w+32). LDS reduce over waves, then per-pixel
// cosine -> shared class bins -> global atomics into ws[scale*64 + {0..20 sim, 32..52 cnt}].

#define EPSV 1e-8f

__global__ __launch_bounds__(512)
void msrd_main(const float* __restrict__ f0, const float* __restrict__ fo0,
               const float* __restrict__ f1, const float* __restrict__ fo1,
               const float* __restrict__ f2, const float* __restrict__ fo2,
               const float* __restrict__ f3, const float* __restrict__ fo3,
               const int*   __restrict__ labels,
               const int*   __restrict__ p_nclass,
               float* __restrict__ ws)
{
    int bid = blockIdx.x;
    int scale, lb, logW, logHW, sshift;
    const float *f, *fo;
    // blocks: [0,512) scale0, [512,640) scale1, [640,672) scale2, [672,680) scale3
    if (bid < 512)      { scale = 0; lb = bid;       f = f0; fo = fo0; logW = 7; logHW = 14; sshift = 2; }
    else if (bid < 640) { scale = 1; lb = bid - 512; f = f1; fo = fo1; logW = 6; logHW = 12; sshift = 3; }
    else if (bid < 672) { scale = 2; lb = bid - 640; f = f2; fo = fo2; logW = 5; logHW = 10; sshift = 4; }
    else                { scale = 3; lb = bid - 672; f = f3; fo = fo3; logW = 4; logHW = 8;  sshift = 5; }
    const int HW = 1 << logHW;
    const int W  = 1 << logW;

    const int tid  = threadIdx.x;
    const int wave = tid >> 6;
    const int lane = tid & 63;

    const int g   = lb * 64 + lane;   // pixel-group index within scale
    const int pix = g << 2;           // flat pixel base (b*HW + h*W + w), w % 4 == 0
    const int b   = pix >> logHW;
    const int rem = pix & (HW - 1);

    const int c0 = wave * 32;
    const float4* __restrict__ fp  = (const float4*)(f  + (size_t)(b * 256 + c0) * HW + rem);
    const float4* __restrict__ fop = (const float4*)(fo + (size_t)(b * 256 + c0) * HW + rem);
    const int str4 = HW >> 2;         // float4 stride between channels

    float dx=0.f,dy=0.f,dz=0.f,dw=0.f;
    float ax=0.f,ay=0.f,az=0.f,aw=0.f;
    float bx=0.f,by=0.f,bz=0.f,bw=0.f;
    #pragma unroll 4
    for (int c = 0; c < 32; ++c) {
        float4 x = fp[c * str4];
        float4 y = fop[c * str4];
        dx = fmaf(x.x, y.x, dx); dy = fmaf(x.y, y.y, dy);
        dz = fmaf(x.z, y.z, dz); dw = fmaf(x.w, y.w, dw);
        ax = fmaf(x.x, x.x, ax); ay = fmaf(x.y, x.y, ay);
        az = fmaf(x.z, x.z, az); aw = fmaf(x.w, x.w, aw);
        bx = fmaf(y.x, y.x, bx); by = fmaf(y.y, y.y, by);
        bz = fmaf(y.z, y.z, bz); bw = fmaf(y.w, y.w, bw);
    }

    __shared__ float4 sD[8][64], sA[8][64], sB[8][64];
    __shared__ float bin_sim[32], bin_cnt[32];
    if (tid < 32) { bin_sim[tid] = 0.f; bin_cnt[tid] = 0.f; }
    sD[wave][lane] = make_float4(dx,dy,dz,dw);
    sA[wave][lane] = make_float4(ax,ay,az,aw);
    sB[wave][lane] = make_float4(bx,by,bz,bw);
    __syncthreads();

    if (wave == 0) {
        float4 D = sD[0][lane], A = sA[0][lane], Bv = sB[0][lane];
        #pragma unroll
        for (int w = 1; w < 8; ++w) {
            float4 t;
            t = sD[w][lane]; D.x += t.x; D.y += t.y; D.z += t.z; D.w += t.w;
            t = sA[w][lane]; A.x += t.x; A.y += t.y; A.z += t.z; A.w += t.w;
            t = sB[w][lane]; Bv.x += t.x; Bv.y += t.y; Bv.z += t.z; Bv.w += t.w;
        }
        const int nclass  = *p_nclass;
        const int labbase = b << 18;  // b * 512 * 512
        float Dv[4] = {D.x, D.y, D.z, D.w};
        float Av[4] = {A.x, A.y, A.z, A.w};
        float Bw[4] = {Bv.x, Bv.y, Bv.z, Bv.w};
        #pragma unroll
        for (int j = 0; j < 4; ++j) {
            float na  = fmaxf(sqrtf(Av[j]), EPSV);
            float nb  = fmaxf(sqrtf(Bw[j]), EPSV);
            float sim = Dv[j] / (na * nb);
            int p    = rem + j;            // stays within row: rem%4==0, W%4==0
            int h    = p >> logW;
            int col  = p & (W - 1);
            int lidx = labbase + ((h << sshift) << 9) + (col << sshift);
            int lab  = labels[lidx];
            if ((unsigned)lab < (unsigned)nclass) {
                atomicAdd(&bin_sim[lab], sim);
                atomicAdd(&bin_cnt[lab], 1.0f);
            }
        }
    }
    __syncthreads();

    if (tid < 32) {
        float s = bin_sim[tid], c = bin_cnt[tid];
        if (s != 0.f || c != 0.f) {
            atomicAdd(&ws[scale * 64 + tid],      s);
            atomicAdd(&ws[scale * 64 + 32 + tid], c);
        }
    }
}

__global__ void msrd_final(const float* __restrict__ ws,
                           const int* __restrict__ p_nclass,
                           const int* __restrict__ p_nold,
                           float* __restrict__ out)
{
    if (threadIdx.x == 0 && blockIdx.x == 0) {
        const int nc = *p_nclass;
        const int no = *p_nold;
        const float wgt[4] = {1.f, 2.f, 3.f, 4.f};
        float loss = 0.f;
        for (int s = 0; s < 4; ++s) {
            float sl = 0.f;
            for (int c = 0; c < nc && c < 32; ++c) {
                float seg = ws[s * 64 + c];
                float cnt = ws[s * 64 + 32 + c];
                if (cnt > 0.f) {
                    float factor = (c == 0) ? (float)no / (float)nc
                                            : (c <= no ? 1.f : 0.f);
                    sl += factor * (1.f - seg / fmaxf(cnt, 1.f));
                }
            }
            loss += wgt[s] * sl;
        }
        out[0] = loss;
    }
}

extern "C" void kernel_launch(void* const* d_in, const int* in_sizes, int n_in,
                              void* d_out, int out_size, void* d_ws, size_t ws_size,
                              hipStream_t stream) {
    // setup_inputs order: pseudo_labels, f0, fo0, f1, fo1, f2, fo2, f3, fo3, num_class, num_old_class
    const int*   labels = (const int*)  d_in[0];
    const float* f0  = (const float*)d_in[1];
    const float* fo0 = (const float*)d_in[2];
    const float* f1  = (const float*)d_in[3];
    const float* fo1 = (const float*)d_in[4];
    const float* f2  = (const float*)d_in[5];
    const float* fo2 = (const float*)d_in[6];
    const float* f3  = (const float*)d_in[7];
    const float* fo3 = (const float*)d_in[8];
    const int* p_nclass = (const int*)d_in[9];
    const int* p_nold   = (const int*)d_in[10];
    float* out = (float*)d_out;
    float* ws  = (float*)d_ws;

    hipMemsetAsync(ws, 0, 4 * 64 * sizeof(float), stream);
    msrd_main<<<dim3(680), dim3(512), 0, stream>>>(f0, fo0, f1, fo1, f2, fo2, f3, fo3,
                                                   labels, p_nclass, ws);
    msrd_final<<<dim3(1), dim3(64), 0, stream>>>(ws, p_nclass, p_nold, out);
}

// Round 2
// 360.492 us; speedup vs baseline: 1.0010x; 1.0010x over previous
//
#include <hip/hip_runtime.h>
#include <math.h>

// Multi-scale region distillation loss — v2 (deep-MLP restructure).
// Scales: (H,W) = (128,128),(64,64),(32,32),(16,16); B=8, C=256; labels 8x1x512x512.
// Block = 512 threads = 8 waves. Each block: 32 pixel-groups (4 px each, float4).
// Wave w handles channel chunk [32w, 32w+32); within a wave, lane = half*32+gi:
// lane covers group gi, channels [32w+16*half, +16), explicitly batched 8-deep
// (16 float4 loads in flight). Halves combined via shfl_xor(32), waves via LDS,
// then per-pixel cosine -> shared class bins -> global atomics into
// ws[scale*64 + {0..31 sim, 32..63 cnt}].

#define EPSV 1e-8f

__global__ __launch_bounds__(512)
void msrd_main(const float* __restrict__ f0, const float* __restrict__ fo0,
               const float* __restrict__ f1, const float* __restrict__ fo1,
               const float* __restrict__ f2, const float* __restrict__ fo2,
               const float* __restrict__ f3, const float* __restrict__ fo3,
               const int*   __restrict__ labels,
               const int*   __restrict__ p_nclass,
               float* __restrict__ ws)
{
    int bid = blockIdx.x;
    int scale, lb, logW, logHW, sshift;
    const float *f, *fo;
    // blocks (32 groups each): [0,1024) s0, [1024,1280) s1, [1280,1344) s2, [1344,1360) s3
    if (bid < 1024)      { scale = 0; lb = bid;        f = f0; fo = fo0; logW = 7; logHW = 14; sshift = 2; }
    else if (bid < 1280) { scale = 1; lb = bid - 1024; f = f1; fo = fo1; logW = 6; logHW = 12; sshift = 3; }
    else if (bid < 1344) { scale = 2; lb = bid - 1280; f = f2; fo = fo2; logW = 5; logHW = 10; sshift = 4; }
    else                 { scale = 3; lb = bid - 1344; f = f3; fo = fo3; logW = 4; logHW = 8;  sshift = 5; }
    const int HW = 1 << logHW;
    const int W  = 1 << logW;

    const int tid  = threadIdx.x;
    const int wave = tid >> 6;
    const int lane = tid & 63;
    const int half = lane >> 5;   // which 16-channel half of the wave's 32-chan chunk
    const int gi   = lane & 31;   // group index within block

    const int g   = lb * 32 + gi;     // pixel-group index within scale
    const int pix = g << 2;           // flat pixel base (b*HW + h*W + w), w % 4 == 0
    const int b   = pix >> logHW;     // whole wave-half stays within one image
    const int rem = pix & (HW - 1);

    const int c0 = wave * 32 + half * 16;
    const float* __restrict__ fpb  = f  + (((size_t)(b * 256 + c0)) << logHW) + rem;
    const float* __restrict__ fopb = fo + (((size_t)(b * 256 + c0)) << logHW) + rem;

    float dx=0.f,dy=0.f,dz=0.f,dw=0.f;
    float ax=0.f,ay=0.f,az=0.f,aw=0.f;
    float bx=0.f,by=0.f,bz=0.f,bw=0.f;

    // two batches of 8 channels; 16 float4 loads issued before any use
    #pragma unroll
    for (int batch = 0; batch < 2; ++batch) {
        float4 X[8], Y[8];
        const size_t cb = (size_t)(batch * 8) << logHW;
        #pragma unroll
        for (int j = 0; j < 8; ++j)
            X[j] = *(const float4*)(fpb + cb + ((size_t)j << logHW));
        #pragma unroll
        for (int j = 0; j < 8; ++j)
            Y[j] = *(const float4*)(fopb + cb + ((size_t)j << logHW));
        #pragma unroll
        for (int j = 0; j < 8; ++j) {
            float4 x = X[j], y = Y[j];
            dx = fmaf(x.x, y.x, dx); dy = fmaf(x.y, y.y, dy);
            dz = fmaf(x.z, y.z, dz); dw = fmaf(x.w, y.w, dw);
            ax = fmaf(x.x, x.x, ax); ay = fmaf(x.y, x.y, ay);
            az = fmaf(x.z, x.z, az); aw = fmaf(x.w, x.w, aw);
            bx = fmaf(y.x, y.x, bx); by = fmaf(y.y, y.y, by);
            bz = fmaf(y.z, y.z, bz); bw = fmaf(y.w, y.w, bw);
        }
    }

    // combine channel halves: xor-32 butterfly over the 12 partials
    dx += __shfl_xor(dx, 32); dy += __shfl_xor(dy, 32);
    dz += __shfl_xor(dz, 32); dw += __shfl_xor(dw, 32);
    ax += __shfl_xor(ax, 32); ay += __shfl_xor(ay, 32);
    az += __shfl_xor(az, 32); aw += __shfl_xor(aw, 32);
    bx += __shfl_xor(bx, 32); by += __shfl_xor(by, 32);
    bz += __shfl_xor(bz, 32); bw += __shfl_xor(bw, 32);

    __shared__ float4 sD[8][32], sA[8][32], sB[8][32];
    __shared__ float bin_sim[32], bin_cnt[32];
    if (tid < 32) { bin_sim[tid] = 0.f; bin_cnt[tid] = 0.f; }
    if (half == 0) {
        sD[wave][gi] = make_float4(dx,dy,dz,dw);
        sA[wave][gi] = make_float4(ax,ay,az,aw);
        sB[wave][gi] = make_float4(bx,by,bz,bw);
    }
    __syncthreads();

    if (tid < 32) {  // wave 0, half 0: lane gi finalizes group gi (its own b/rem)
        float4 D = sD[0][gi], A = sA[0][gi], Bv = sB[0][gi];
        #pragma unroll
        for (int w = 1; w < 8; ++w) {
            float4 t;
            t = sD[w][gi]; D.x += t.x; D.y += t.y; D.z += t.z; D.w += t.w;
            t = sA[w][gi]; A.x += t.x; A.y += t.y; A.z += t.z; A.w += t.w;
            t = sB[w][gi]; Bv.x += t.x; Bv.y += t.y; Bv.z += t.z; Bv.w += t.w;
        }
        const int nclass  = *p_nclass;
        const int labbase = b << 18;  // b * 512 * 512
        float Dv[4] = {D.x, D.y, D.z, D.w};
        float Av[4] = {A.x, A.y, A.z, A.w};
        float Bw[4] = {Bv.x, Bv.y, Bv.z, Bv.w};
        #pragma unroll
        for (int j = 0; j < 4; ++j) {
            float na  = fmaxf(sqrtf(Av[j]), EPSV);
            float nb  = fmaxf(sqrtf(Bw[j]), EPSV);
            float sim = Dv[j] / (na * nb);
            int p    = rem + j;            // stays within row: rem%4==0, W%4==0
            int h    = p >> logW;
            int col  = p & (W - 1);
            int lidx = labbase + ((h << sshift) << 9) + (col << sshift);
            int lab  = labels[lidx];
            if ((unsigned)lab < (unsigned)nclass) {
                atomicAdd(&bin_sim[lab], sim);
                atomicAdd(&bin_cnt[lab], 1.0f);
            }
        }
    }
    __syncthreads();

    if (tid < 32) {
        float s = bin_sim[tid], c = bin_cnt[tid];
        if (s != 0.f || c != 0.f) {
            atomicAdd(&ws[scale * 64 + tid],      s);
            atomicAdd(&ws[scale * 64 + 32 + tid], c);
        }
    }
}

__global__ void msrd_final(const float* __restrict__ ws,
                           const int* __restrict__ p_nclass,
                           const int* __restrict__ p_nold,
                           float* __restrict__ out)
{
    if (threadIdx.x == 0 && blockIdx.x == 0) {
        const int nc = *p_nclass;
        const int no = *p_nold;
        const float wgt[4] = {1.f, 2.f, 3.f, 4.f};
        float loss = 0.f;
        for (int s = 0; s < 4; ++s) {
            float sl = 0.f;
            for (int c = 0; c < nc && c < 32; ++c) {
                float seg = ws[s * 64 + c];
                float cnt = ws[s * 64 + 32 + c];
                if (cnt > 0.f) {
                    float factor = (c == 0) ? (float)no / (float)nc
                                            : (c <= no ? 1.f : 0.f);
                    sl += factor * (1.f - seg / fmaxf(cnt, 1.f));
                }
            }
            loss += wgt[s] * sl;
        }
        out[0] = loss;
    }
}

extern "C" void kernel_launch(void* const* d_in, const int* in_sizes, int n_in,
                              void* d_out, int out_size, void* d_ws, size_t ws_size,
                              hipStream_t stream) {
    // setup_inputs order: pseudo_labels, f0, fo0, f1, fo1, f2, fo2, f3, fo3, num_class, num_old_class
    const int*   labels = (const int*)  d_in[0];
    const float* f0  = (const float*)d_in[1];
    const float* fo0 = (const float*)d_in[2];
    const float* f1  = (const float*)d_in[3];
    const float* fo1 = (const float*)d_in[4];
    const float* f2  = (const float*)d_in[5];
    const float* fo2 = (const float*)d_in[6];
    const float* f3  = (const float*)d_in[7];
    const float* fo3 = (const float*)d_in[8];
    const int* p_nclass = (const int*)d_in[9];
    const int* p_nold   = (const int*)d_in[10];
    float* out = (float*)d_out;
    float* ws  = (float*)d_ws;

    hipMemsetAsync(ws, 0, 4 * 64 * sizeof(float), stream);
    msrd_main<<<dim3(1360), dim3(512), 0, stream>>>(f0, fo0, f1, fo1, f2, fo2, f3, fo3,
                                                    labels, p_nclass, ws);
    msrd_final<<<dim3(1), dim3(64), 0, stream>>>(ws, p_nclass, p_nold, out);
}